// Round 1
// baseline (318.327 us; speedup 1.0000x reference)
//
#include <hip/hip_runtime.h>

#define HID 128

// ---------------------------------------------------------------------------
// Kernel 1: scatter-add distances into per-node aggregate.
// agg[row[e]] += dist[e]   (scaled by 1/100 at consumption time)
// ---------------------------------------------------------------------------
__global__ void scatter_kernel(const int* __restrict__ rows,
                               const float* __restrict__ dist,
                               float* __restrict__ agg,
                               int n_edges) {
    int e = blockIdx.x * blockDim.x + threadIdx.x;
    if (e < n_edges) {
        atomicAdd(&agg[rows[e]], dist[e]);
    }
}

// ---------------------------------------------------------------------------
// Kernel 2: node MLP with residual, thread-per-node.
//   ninp = [h[i,:], agg[i]/100]                       (129)
//   t    = silu(ninp @ W1 + b1)                       (128)
//   u    = t @ W2 + b2                                (128)
//   out  = h[i,:] + u
// Weight rows are wave-uniform -> scalar loads (s_load) broadcast to all
// lanes; accumulators live in VGPRs (128 each layer, reused). t goes through
// LDS so layer 2 can index it with a runtime k without register spills.
// Block = 64 threads (1 wave); LDS slice stride 132 floats (16B aligned).
// ---------------------------------------------------------------------------
__global__ __launch_bounds__(64, 1) void node_mlp_kernel(
    const float* __restrict__ h,
    const float* __restrict__ agg,
    const float* __restrict__ W1,   // [129][128] row-major
    const float* __restrict__ b1,   // [128]
    const float* __restrict__ W2,   // [128][128] row-major
    const float* __restrict__ b2,   // [128]
    float* __restrict__ out,
    int n_nodes)
{
    __shared__ float t_lds[64 * 132];

    const int node = blockIdx.x * 64 + threadIdx.x;
    const bool active = node < n_nodes;
    const float* hrow = h + (size_t)(active ? node : 0) * HID;

    // ---------------- layer 1: t = ninp @ W1 + b1 ----------------
    float t[HID];
#pragma unroll
    for (int j = 0; j < HID; ++j) t[j] = b1[j];

    for (int k = 0; k < HID; k += 4) {
        float4 x = *(const float4*)(hrow + k);
        const float* w = W1 + (size_t)k * HID;
#pragma unroll
        for (int j = 0; j < HID; ++j) t[j] = fmaf(x.x, w[j], t[j]);
#pragma unroll
        for (int j = 0; j < HID; ++j) t[j] = fmaf(x.y, w[HID + j], t[j]);
#pragma unroll
        for (int j = 0; j < HID; ++j) t[j] = fmaf(x.z, w[2 * HID + j], t[j]);
#pragma unroll
        for (int j = 0; j < HID; ++j) t[j] = fmaf(x.w, w[3 * HID + j], t[j]);
    }
    // agg contribution (129th input row of W1)
    {
        float a = (active ? agg[node] : 0.0f) * 0.01f;
        const float* w = W1 + (size_t)HID * HID;
#pragma unroll
        for (int j = 0; j < HID; ++j) t[j] = fmaf(a, w[j], t[j]);
    }

    // silu, park t in LDS (own slice; no barrier needed, one wave per block)
    float* slice = &t_lds[threadIdx.x * 132];
#pragma unroll
    for (int j = 0; j < HID; ++j) {
        float v = t[j];
        v = v / (1.0f + __expf(-v));
        slice[j] = v;
    }

    // ---------------- layer 2: u = t @ W2 + b2 ----------------
    float u[HID];
#pragma unroll
    for (int j = 0; j < HID; ++j) u[j] = b2[j];

    for (int k = 0; k < HID; k += 4) {
        float4 tv = *(const float4*)(slice + k);
        const float* w = W2 + (size_t)k * HID;
#pragma unroll
        for (int j = 0; j < HID; ++j) u[j] = fmaf(tv.x, w[j], u[j]);
#pragma unroll
        for (int j = 0; j < HID; ++j) u[j] = fmaf(tv.y, w[HID + j], u[j]);
#pragma unroll
        for (int j = 0; j < HID; ++j) u[j] = fmaf(tv.z, w[2 * HID + j], u[j]);
#pragma unroll
        for (int j = 0; j < HID; ++j) u[j] = fmaf(tv.w, w[3 * HID + j], u[j]);
    }

    // ---------------- residual + store ----------------
    if (active) {
        float* orow = out + (size_t)node * HID;
#pragma unroll
        for (int j = 0; j < HID; j += 4) {
            float4 hv = *(const float4*)(hrow + j);
            float4 o;
            o.x = hv.x + u[j];
            o.y = hv.y + u[j + 1];
            o.z = hv.z + u[j + 2];
            o.w = hv.w + u[j + 3];
            *(float4*)(orow + j) = o;
        }
    }
}

// ---------------------------------------------------------------------------
// Launch
// Inputs (setup_inputs order):
//  0 h          [50000*128] f32
//  1 edges      [2*800000]  int32 (row = first E entries)
//  2 distances  [800000]    f32
//  3 W_e1, 4 b_e1, 5 W_e2, 6 b_e2, 7 W_ei, 8 b_ei   (DEAD CODE - unused)
//  9 W_n1       [129*128]   f32
// 10 b_n1       [128]       f32
// 11 W_n2       [128*128]   f32
// 12 b_n2       [128]       f32
// ---------------------------------------------------------------------------
extern "C" void kernel_launch(void* const* d_in, const int* in_sizes, int n_in,
                              void* d_out, int out_size, void* d_ws, size_t ws_size,
                              hipStream_t stream) {
    const float* h     = (const float*)d_in[0];
    const int*   edges = (const int*)d_in[1];
    const float* dist  = (const float*)d_in[2];
    const float* W1    = (const float*)d_in[9];
    const float* b1    = (const float*)d_in[10];
    const float* W2    = (const float*)d_in[11];
    const float* b2    = (const float*)d_in[12];
    float* out = (float*)d_out;

    const int n_nodes = in_sizes[0] / HID;
    const int n_edges = in_sizes[2];
    const int* rows = edges;  // edges[0, :] in the [2, E] layout

    float* agg = (float*)d_ws;  // n_nodes floats of scratch

    // zero the aggregate buffer (d_ws is poisoned before every launch)
    hipMemsetAsync(agg, 0, (size_t)n_nodes * sizeof(float), stream);

    scatter_kernel<<<(n_edges + 255) / 256, 256, 0, stream>>>(rows, dist, agg, n_edges);

    const int blocks = (n_nodes + 63) / 64;
    node_mlp_kernel<<<blocks, 64, 0, stream>>>(h, agg, W1, b1, W2, b2, out, n_nodes);
}

// Round 2
// 180.006 us; speedup vs baseline: 1.7684x; 1.7684x over previous
//
#include <hip/hip_runtime.h>

#define HID 128

typedef __attribute__((ext_vector_type(8))) short short8;   // bf16x8 A/B frag (4 VGPRs)
typedef __attribute__((ext_vector_type(4))) float floatx4;  // C/D frag

// fp32 -> bf16 (RNE) as raw short
__device__ __forceinline__ short f2bf(float f) {
    unsigned u = __builtin_bit_cast(unsigned, f);
    unsigned r = (u + 0x7FFFu + ((u >> 16) & 1u)) >> 16;
    return (short)r;
}

// ---------------------------------------------------------------------------
// Kernel 1: scatter-add distances into per-node aggregate (x4 per thread).
// ---------------------------------------------------------------------------
__global__ void scatter_kernel(const int* __restrict__ rows,
                               const float* __restrict__ dist,
                               float* __restrict__ agg,
                               int n_edges) {
    int i = (blockIdx.x * blockDim.x + threadIdx.x) * 4;
    if (i + 3 < n_edges) {
        int4   r = *(const int4*)(rows + i);
        float4 d = *(const float4*)(dist + i);
        atomicAdd(&agg[r.x], d.x);
        atomicAdd(&agg[r.y], d.y);
        atomicAdd(&agg[r.z], d.z);
        atomicAdd(&agg[r.w], d.w);
    } else {
        for (; i < n_edges; ++i) atomicAdd(&agg[rows[i]], dist[i]);
    }
}

// ---------------------------------------------------------------------------
// Kernel 2: transpose + bf16-convert the two 128x128 weight blocks.
// W1t[n][k] = bf16(W1[k][n]), W2t[n][k] = bf16(W2[k][n]).  (W1 row 128, the
// agg row, stays fp32 and is applied in the epilogue.)
// ---------------------------------------------------------------------------
__global__ void convert_weights(const float* __restrict__ W1,
                                const float* __restrict__ W2,
                                short* __restrict__ W1t,
                                short* __restrict__ W2t) {
    int t = blockIdx.x * blockDim.x + threadIdx.x;   // 0..32767
    int idx = t & 16383;
    int n = idx & 127, k = idx >> 7;
    if (t < 16384) W1t[n * 128 + k] = f2bf(W1[k * 128 + n]);
    else           W2t[n * 128 + k] = f2bf(W2[k * 128 + n]);
}

// ---------------------------------------------------------------------------
// Kernel 3: node MLP via bf16 MFMA, one wave per 16 nodes.
//   t = silu(h@W1a + agg*w_agg + b1); out = h + t@W2 + b2
// A-frag: lane holds A[m=lane&15][k=quad*8+j] -> 16B contiguous from h row.
// B-frag: lane holds B[k=quad*8+j][n=lane&15] -> 16B contiguous from Wt[n][k].
// C/D:    lane holds col=lane&15, row=quad*4+reg.
// t goes through LDS (stride 136 bf16 = 272B: 16B-aligned rows, 2-way banks
// = free) to convert C-layout -> A-layout for the second GEMM.
// ---------------------------------------------------------------------------
__global__ __launch_bounds__(64) void node_mlp_mfma(
    const float* __restrict__ h,
    const float* __restrict__ agg,
    const short* __restrict__ W1t,   // [128][128] bf16 (n-major)
    const short* __restrict__ W2t,   // [128][128] bf16 (n-major)
    const float* __restrict__ W1,    // fp32, for row 128 (agg weight row)
    const float* __restrict__ b1,
    const float* __restrict__ b2,
    float* __restrict__ out,
    int n_nodes)
{
    __shared__ short t_lds[16 * 136];

    const int lane = threadIdx.x;
    const int m16  = lane & 15;
    const int quad = lane >> 4;
    const int node0 = blockIdx.x * 16;

    // ---- A fragments for layer 1 (h rows, fp32 -> bf16 in regs)
    short8 a1[4];
    {
        int row = node0 + m16;
        if (row >= n_nodes) row = n_nodes - 1;
        const float* hr = h + (size_t)row * HID + quad * 8;
#pragma unroll
        for (int kc = 0; kc < 4; ++kc) {
            float4 x0 = *(const float4*)(hr + kc * 32);
            float4 x1 = *(const float4*)(hr + kc * 32 + 4);
            short8 v;
            v[0] = f2bf(x0.x); v[1] = f2bf(x0.y); v[2] = f2bf(x0.z); v[3] = f2bf(x0.w);
            v[4] = f2bf(x1.x); v[5] = f2bf(x1.y); v[6] = f2bf(x1.z); v[7] = f2bf(x1.w);
            a1[kc] = v;
        }
    }

    // agg values for this lane's 4 C-rows (quad*4 + r), scaled by 1/100
    float4 a4 = *(const float4*)(agg + node0 + quad * 4);
    a4.x *= 0.01f; a4.y *= 0.01f; a4.z *= 0.01f; a4.w *= 0.01f;

    // ---- layer 1: 8 col-tiles of 16, K=128 in 4 MFMA steps each
#pragma unroll
    for (int nt = 0; nt < 8; ++nt) {
        floatx4 acc = {0.f, 0.f, 0.f, 0.f};
        const short* wb = W1t + (size_t)(nt * 16 + m16) * 128 + quad * 8;
#pragma unroll
        for (int kc = 0; kc < 4; ++kc) {
            short8 bfr = *(const short8*)(wb + kc * 32);
            acc = __builtin_amdgcn_mfma_f32_16x16x32_bf16(a1[kc], bfr, acc, 0, 0, 0);
        }
        int col = nt * 16 + m16;
        float bias = b1[col];
        float wagg = W1[128 * HID + col];
        float av[4] = {a4.x, a4.y, a4.z, a4.w};
#pragma unroll
        for (int r = 0; r < 4; ++r) {
            float v = acc[r] + bias + av[r] * wagg;
            float sg = __builtin_amdgcn_rcpf(1.0f + __expf(-v));
            v *= sg;                       // silu
            t_lds[(quad * 4 + r) * 136 + col] = f2bf(v);
        }
    }

    __syncthreads();   // LDS write -> cross-lane read ordering

    // ---- A fragments for layer 2 from LDS (A-layout reads, 16B aligned)
    short8 a2[4];
#pragma unroll
    for (int kc = 0; kc < 4; ++kc)
        a2[kc] = *(const short8*)(t_lds + m16 * 136 + kc * 32 + quad * 8);

    // ---- layer 2 + residual epilogue
#pragma unroll
    for (int nt = 0; nt < 8; ++nt) {
        floatx4 acc = {0.f, 0.f, 0.f, 0.f};
        const short* wb = W2t + (size_t)(nt * 16 + m16) * 128 + quad * 8;
#pragma unroll
        for (int kc = 0; kc < 4; ++kc) {
            short8 bfr = *(const short8*)(wb + kc * 32);
            acc = __builtin_amdgcn_mfma_f32_16x16x32_bf16(a2[kc], bfr, acc, 0, 0, 0);
        }
        int col = nt * 16 + m16;
        float bias = b2[col];
#pragma unroll
        for (int r = 0; r < 4; ++r) {
            int row = node0 + quad * 4 + r;
            if (row < n_nodes) {
                size_t off = (size_t)row * HID + col;
                out[off] = h[off] + acc[r] + bias;
            }
        }
    }
}

// ---------------------------------------------------------------------------
// Launch.  Inputs (setup_inputs order):
//  0 h[50000*128] f32 | 1 edges[2*800000] i32 | 2 distances[800000] f32
//  3..8 edge-MLP weights (DEAD CODE, unused)
//  9 W_n1[129*128] | 10 b_n1[128] | 11 W_n2[128*128] | 12 b_n2[128]
// d_ws layout: agg f32[50048] | W1t bf16[16384] | W2t bf16[16384]
// ---------------------------------------------------------------------------
extern "C" void kernel_launch(void* const* d_in, const int* in_sizes, int n_in,
                              void* d_out, int out_size, void* d_ws, size_t ws_size,
                              hipStream_t stream) {
    const float* h     = (const float*)d_in[0];
    const int*   edges = (const int*)d_in[1];
    const float* dist  = (const float*)d_in[2];
    const float* W1    = (const float*)d_in[9];
    const float* b1    = (const float*)d_in[10];
    const float* W2    = (const float*)d_in[11];
    const float* b2    = (const float*)d_in[12];
    float* out = (float*)d_out;

    const int n_nodes = in_sizes[0] / HID;
    const int n_edges = in_sizes[2];
    const int* rows = edges;   // edges[0, :]

    float* agg  = (float*)d_ws;
    short* W1t  = (short*)((char*)d_ws + 50048 * sizeof(float));
    short* W2t  = W1t + 16384;

    hipMemsetAsync(agg, 0, (size_t)n_nodes * sizeof(float), stream);

    convert_weights<<<128, 256, 0, stream>>>(W1, W2, W1t, W2t);

    const int sthreads = (n_edges + 3) / 4;
    scatter_kernel<<<(sthreads + 255) / 256, 256, 0, stream>>>(rows, dist, agg, n_edges);

    const int blocks = (n_nodes + 15) / 16;
    node_mlp_mfma<<<blocks, 64, 0, stream>>>(h, agg, W1t, W2t, W1, b1, b2, out, n_nodes);
}

// Round 3
// 177.512 us; speedup vs baseline: 1.7933x; 1.0140x over previous
//
#include <hip/hip_runtime.h>

#define HID 128
#define NODE_PAD 50048   // padded node count (multiple of 16; *4B is 16B-aligned)

typedef __attribute__((ext_vector_type(8))) short short8;   // bf16x8 A/B frag (4 VGPRs)
typedef __attribute__((ext_vector_type(4))) float floatx4;  // C/D frag

// fp32 -> bf16 (RNE) as raw short
__device__ __forceinline__ short f2bf(float f) {
    unsigned u = __builtin_bit_cast(unsigned, f);
    unsigned r = (u + 0x7FFFu + ((u >> 16) & 1u)) >> 16;
    return (short)r;
}

// ---------------------------------------------------------------------------
// Kernel 1: scatter-add distances into C privatized partial aggregates.
// Block b atomics into copy (b & cmask) -> per-cacheline serialization /C.
// ---------------------------------------------------------------------------
__global__ void scatter_kernel(const int* __restrict__ rows,
                               const float* __restrict__ dist,
                               float* __restrict__ part,
                               int n_edges, int cmask) {
    float* myagg = part + (size_t)(blockIdx.x & cmask) * NODE_PAD;
    int i = (blockIdx.x * blockDim.x + threadIdx.x) * 4;
    if (i + 3 < n_edges) {
        int4   r = *(const int4*)(rows + i);
        float4 d = *(const float4*)(dist + i);
        atomicAdd(&myagg[r.x], d.x);
        atomicAdd(&myagg[r.y], d.y);
        atomicAdd(&myagg[r.z], d.z);
        atomicAdd(&myagg[r.w], d.w);
    } else {
        for (; i < n_edges; ++i) atomicAdd(&myagg[rows[i]], dist[i]);
    }
}

// ---------------------------------------------------------------------------
// Kernel 2: transpose + bf16-convert the two 128x128 weight blocks.
// W1t[n][k] = bf16(W1[k][n]), W2t[n][k] = bf16(W2[k][n]).  (W1 row 128, the
// agg row, stays fp32 and is applied in the epilogue.)
// ---------------------------------------------------------------------------
__global__ void convert_weights(const float* __restrict__ W1,
                                const float* __restrict__ W2,
                                short* __restrict__ W1t,
                                short* __restrict__ W2t) {
    int t = blockIdx.x * blockDim.x + threadIdx.x;   // 0..32767
    int idx = t & 16383;
    int n = idx & 127, k = idx >> 7;
    if (t < 16384) W1t[n * 128 + k] = f2bf(W1[k * 128 + n]);
    else           W2t[n * 128 + k] = f2bf(W2[k * 128 + n]);
}

// ---------------------------------------------------------------------------
// Kernel 3: node MLP via bf16 MFMA, one wave per 16 nodes.
//   agg = sum_c part[c][node]  (reduce of privatized copies, fused here)
//   t = silu(h@W1a + agg*0.01*w_agg + b1); out = h + t@W2 + b2
// A-frag: lane holds A[m=lane&15][k=quad*8+j] -> 16B contiguous from h row.
// B-frag: lane holds B[k=quad*8+j][n=lane&15] -> 16B contiguous from Wt[n][k].
// C/D:    lane holds col=lane&15, row=quad*4+reg.
// t goes through LDS (stride 136 bf16) to convert C-layout -> A-layout.
// ---------------------------------------------------------------------------
__global__ __launch_bounds__(64) void node_mlp_mfma(
    const float* __restrict__ h,
    const float* __restrict__ part,  // [C][NODE_PAD] partial aggregates
    const short* __restrict__ W1t,   // [128][128] bf16 (n-major)
    const short* __restrict__ W2t,   // [128][128] bf16 (n-major)
    const float* __restrict__ W1,    // fp32, for row 128 (agg weight row)
    const float* __restrict__ b1,
    const float* __restrict__ b2,
    float* __restrict__ out,
    int n_nodes, int ncopies)
{
    __shared__ short t_lds[16 * 136];

    const int lane = threadIdx.x;
    const int m16  = lane & 15;
    const int quad = lane >> 4;
    const int node0 = blockIdx.x * 16;

    // ---- A fragments for layer 1 (h rows, fp32 -> bf16 in regs)
    short8 a1[4];
    {
        int row = node0 + m16;
        if (row >= n_nodes) row = n_nodes - 1;
        const float* hr = h + (size_t)row * HID + quad * 8;
#pragma unroll
        for (int kc = 0; kc < 4; ++kc) {
            float4 x0 = *(const float4*)(hr + kc * 32);
            float4 x1 = *(const float4*)(hr + kc * 32 + 4);
            short8 v;
            v[0] = f2bf(x0.x); v[1] = f2bf(x0.y); v[2] = f2bf(x0.z); v[3] = f2bf(x0.w);
            v[4] = f2bf(x1.x); v[5] = f2bf(x1.y); v[6] = f2bf(x1.z); v[7] = f2bf(x1.w);
            a1[kc] = v;
        }
    }

    // agg for this lane's 4 C-rows: sum privatized partials, scale by 1/100
    float4 a4 = {0.f, 0.f, 0.f, 0.f};
    for (int c = 0; c < ncopies; ++c) {
        float4 p = *(const float4*)(part + (size_t)c * NODE_PAD + node0 + quad * 4);
        a4.x += p.x; a4.y += p.y; a4.z += p.z; a4.w += p.w;
    }
    a4.x *= 0.01f; a4.y *= 0.01f; a4.z *= 0.01f; a4.w *= 0.01f;

    // ---- layer 1: 8 col-tiles of 16, K=128 in 4 MFMA steps each
#pragma unroll
    for (int nt = 0; nt < 8; ++nt) {
        floatx4 acc = {0.f, 0.f, 0.f, 0.f};
        const short* wb = W1t + (size_t)(nt * 16 + m16) * 128 + quad * 8;
#pragma unroll
        for (int kc = 0; kc < 4; ++kc) {
            short8 bfr = *(const short8*)(wb + kc * 32);
            acc = __builtin_amdgcn_mfma_f32_16x16x32_bf16(a1[kc], bfr, acc, 0, 0, 0);
        }
        int col = nt * 16 + m16;
        float bias = b1[col];
        float wagg = W1[128 * HID + col];
        float av[4] = {a4.x, a4.y, a4.z, a4.w};
#pragma unroll
        for (int r = 0; r < 4; ++r) {
            float v = acc[r] + bias + av[r] * wagg;
            float sg = __builtin_amdgcn_rcpf(1.0f + __expf(-v));
            v *= sg;                       // silu
            t_lds[(quad * 4 + r) * 136 + col] = f2bf(v);
        }
    }

    __syncthreads();   // LDS write -> cross-lane read ordering

    // ---- A fragments for layer 2 from LDS (A-layout reads, 16B aligned)
    short8 a2[4];
#pragma unroll
    for (int kc = 0; kc < 4; ++kc)
        a2[kc] = *(const short8*)(t_lds + m16 * 136 + kc * 32 + quad * 8);

    // ---- layer 2 + residual epilogue
#pragma unroll
    for (int nt = 0; nt < 8; ++nt) {
        floatx4 acc = {0.f, 0.f, 0.f, 0.f};
        const short* wb = W2t + (size_t)(nt * 16 + m16) * 128 + quad * 8;
#pragma unroll
        for (int kc = 0; kc < 4; ++kc) {
            short8 bfr = *(const short8*)(wb + kc * 32);
            acc = __builtin_amdgcn_mfma_f32_16x16x32_bf16(a2[kc], bfr, acc, 0, 0, 0);
        }
        int col = nt * 16 + m16;
        float bias = b2[col];
#pragma unroll
        for (int r = 0; r < 4; ++r) {
            int row = node0 + quad * 4 + r;
            if (row < n_nodes) {
                size_t off = (size_t)row * HID + col;
                out[off] = h[off] + acc[r] + bias;
            }
        }
    }
}

// ---------------------------------------------------------------------------
// Launch.  Inputs (setup_inputs order):
//  0 h[50000*128] f32 | 1 edges[2*800000] i32 | 2 distances[800000] f32
//  3..8 edge-MLP weights (DEAD CODE, unused)
//  9 W_n1[129*128] | 10 b_n1[128] | 11 W_n2[128*128] | 12 b_n2[128]
// d_ws layout: part f32[C][NODE_PAD] | W1t bf16[16384] | W2t bf16[16384]
// C (privatized copies) auto-sized from ws_size, capped at 16, pow2.
// ---------------------------------------------------------------------------
extern "C" void kernel_launch(void* const* d_in, const int* in_sizes, int n_in,
                              void* d_out, int out_size, void* d_ws, size_t ws_size,
                              hipStream_t stream) {
    const float* h     = (const float*)d_in[0];
    const int*   edges = (const int*)d_in[1];
    const float* dist  = (const float*)d_in[2];
    const float* W1    = (const float*)d_in[9];
    const float* b1    = (const float*)d_in[10];
    const float* W2    = (const float*)d_in[11];
    const float* b2    = (const float*)d_in[12];
    float* out = (float*)d_out;

    const int n_nodes = in_sizes[0] / HID;
    const int n_edges = in_sizes[2];
    const int* rows = edges;   // edges[0, :]

    // choose copy count C (pow2 <= 16) to fit ws_size
    const size_t wbytes = 2 * 16384 * sizeof(short);   // 64 KB for W1t+W2t
    size_t avail = (ws_size > wbytes) ? ws_size - wbytes : 0;
    int C = 1;
    while (C < 16 && (size_t)(C * 2) * NODE_PAD * sizeof(float) <= avail) C *= 2;

    float* part = (float*)d_ws;
    short* W1t  = (short*)((char*)d_ws + (size_t)C * NODE_PAD * sizeof(float));
    short* W2t  = W1t + 16384;

    hipMemsetAsync(part, 0, (size_t)C * NODE_PAD * sizeof(float), stream);

    convert_weights<<<128, 256, 0, stream>>>(W1, W2, W1t, W2t);

    const int sthreads = (n_edges + 3) / 4;
    scatter_kernel<<<(sthreads + 255) / 256, 256, 0, stream>>>(rows, dist, part,
                                                               n_edges, C - 1);

    const int blocks = (n_nodes + 15) / 16;
    node_mlp_mfma<<<blocks, 64, 0, stream>>>(h, part, W1t, W2t, W1, b1, b2, out,
                                             n_nodes, C);
}

// Round 4
// 163.676 us; speedup vs baseline: 1.9449x; 1.0845x over previous
//
#include <hip/hip_runtime.h>

#define HID 128
#define NODE_PAD 50048   // padded node count (multiple of 16; covers 50000)
#define NRANGE 4         // node ranges (LDS histogram per range)
#define RANGE 12512      // NODE_PAD / NRANGE  (48.9 KB of LDS bins)
#define NPART 128        // edge chunks = partial aggregate buffers

typedef __attribute__((ext_vector_type(8))) short short8;   // bf16x8 A/B frag (4 VGPRs)
typedef __attribute__((ext_vector_type(4))) float floatx4;  // C/D frag

// fp32 -> bf16 (RNE) as raw short
__device__ __forceinline__ short f2bf(float f) {
    unsigned u = __builtin_bit_cast(unsigned, f);
    unsigned r = (u + 0x7FFFu + ((u >> 16) & 1u)) >> 16;
    return (short)r;
}

// ---------------------------------------------------------------------------
// Kernel 1: scatter-add with ZERO global atomics.
// Grid = NRANGE * NPART blocks. Block (r,b) builds an LDS histogram of node
// range r over edge chunk b (LDS ds_add_f32 atomics only), then streams the
// bins to part[b][range r] with plain coalesced stores. agg[node] =
// sum_b part[b][node], reduced inside the MLP kernel.
// Round-3 lesson: device-scope fp32 atomicAdd writes through to the fabric
// (~19 G atomics/s ceiling, 32 B/atomic HBM write) — avoid entirely.
// ---------------------------------------------------------------------------
__global__ __launch_bounds__(256) void scatter_lds(const int* __restrict__ rows,
                                                   const float* __restrict__ dist,
                                                   float* __restrict__ part,
                                                   int n_edges) {
    __shared__ float bins[RANGE];
    const int r = blockIdx.x & (NRANGE - 1);
    const int b = blockIdx.x >> 2;
    const int base = r * RANGE;

    for (int i = threadIdx.x; i < RANGE / 4; i += 256)
        ((float4*)bins)[i] = make_float4(0.f, 0.f, 0.f, 0.f);
    __syncthreads();

    const int chunk = (n_edges + NPART - 1) / NPART;
    const int cbeg = b * chunk;
    const int cend = min(cbeg + chunk, n_edges);

    for (int i = cbeg + threadIdx.x * 4; i < cend; i += 256 * 4) {
        if (i + 4 <= cend) {
            int4   rr = *(const int4*)(rows + i);
            float4 dd = *(const float4*)(dist + i);
            if ((unsigned)(rr.x - base) < RANGE) atomicAdd(&bins[rr.x - base], dd.x);
            if ((unsigned)(rr.y - base) < RANGE) atomicAdd(&bins[rr.y - base], dd.y);
            if ((unsigned)(rr.z - base) < RANGE) atomicAdd(&bins[rr.z - base], dd.z);
            if ((unsigned)(rr.w - base) < RANGE) atomicAdd(&bins[rr.w - base], dd.w);
        } else {
            for (int j = i; j < cend; ++j) {
                int rw = rows[j];
                if ((unsigned)(rw - base) < RANGE) atomicAdd(&bins[rw - base], dist[j]);
            }
        }
    }
    __syncthreads();

    float4* dst = (float4*)(part + (size_t)b * NODE_PAD + base);
    for (int i = threadIdx.x; i < RANGE / 4; i += 256)
        dst[i] = ((const float4*)bins)[i];
}

// ---------------------------------------------------------------------------
// Kernel 2: transpose + bf16-convert the two 128x128 weight blocks.
// W1t[n][k] = bf16(W1[k][n]), W2t[n][k] = bf16(W2[k][n]).  (W1 row 128, the
// agg row, stays fp32 and is applied in the epilogue.)
// ---------------------------------------------------------------------------
__global__ void convert_weights(const float* __restrict__ W1,
                                const float* __restrict__ W2,
                                short* __restrict__ W1t,
                                short* __restrict__ W2t) {
    int t = blockIdx.x * blockDim.x + threadIdx.x;   // 0..32767
    int idx = t & 16383;
    int n = idx & 127, k = idx >> 7;
    if (t < 16384) W1t[n * 128 + k] = f2bf(W1[k * 128 + n]);
    else           W2t[n * 128 + k] = f2bf(W2[k * 128 + n]);
}

// ---------------------------------------------------------------------------
// Kernel 3: node MLP via bf16 MFMA. 256-thread blocks = 4 independent waves,
// each wave one 16-node tile (782 blocks vs 3128 single-wave: better wave
// packing / latency hiding; round-3 showed 26% occupancy, VALUBusy 8.7%).
//   agg = sum_b part[b][node]  (reduce of the 128 scatter partials, fused)
//   t = silu(h@W1 + agg*0.01*w_agg + b1); out = h + t@W2 + b2
// A-frag: lane holds A[m=lane&15][k=quad*8+j] -> 16B contiguous from h row.
// B-frag: lane holds B[k=quad*8+j][n=lane&15] -> 16B contiguous from Wt[n][k].
// C/D:    col=lane&15, row=quad*4+reg.  t round-trips LDS (stride 136 bf16)
// to convert C-layout -> A-layout for the second GEMM.
// ---------------------------------------------------------------------------
__global__ __launch_bounds__(256) void node_mlp_mfma(
    const float* __restrict__ h,
    const float* __restrict__ part,  // [NPART][NODE_PAD] partial aggregates
    const short* __restrict__ W1t,   // [128][128] bf16 (n-major)
    const short* __restrict__ W2t,   // [128][128] bf16 (n-major)
    const float* __restrict__ W1,    // fp32, for row 128 (agg weight row)
    const float* __restrict__ b1,
    const float* __restrict__ b2,
    float* __restrict__ out,
    int n_nodes)
{
    __shared__ short t_lds[4][16 * 136];

    const int wv   = threadIdx.x >> 6;
    const int lane = threadIdx.x & 63;
    const int m16  = lane & 15;
    const int quad = lane >> 4;
    const int node0 = blockIdx.x * 64 + wv * 16;

    // ---- A fragments for layer 1 (h rows, fp32 -> bf16 in regs)
    short8 a1[4];
    {
        int row = node0 + m16;
        if (row >= n_nodes) row = n_nodes - 1;
        const float* hr = h + (size_t)row * HID + quad * 8;
#pragma unroll
        for (int kc = 0; kc < 4; ++kc) {
            float4 x0 = *(const float4*)(hr + kc * 32);
            float4 x1 = *(const float4*)(hr + kc * 32 + 4);
            short8 v;
            v[0] = f2bf(x0.x); v[1] = f2bf(x0.y); v[2] = f2bf(x0.z); v[3] = f2bf(x0.w);
            v[4] = f2bf(x1.x); v[5] = f2bf(x1.y); v[6] = f2bf(x1.z); v[7] = f2bf(x1.w);
            a1[kc] = v;
        }
    }

    // agg for this lane's 4 C-rows: reduce the NPART partials (x2 unroll,
    // 2 chains), scale by 1/100. One 64B line per wave per partial.
    float4 s0 = {0.f,0.f,0.f,0.f}, s1 = {0.f,0.f,0.f,0.f};
    {
        const float* pp = part + node0 + quad * 4;
#pragma unroll 4
        for (int c = 0; c < NPART; c += 2) {
            float4 p0 = *(const float4*)(pp + (size_t)c * NODE_PAD);
            float4 p1 = *(const float4*)(pp + (size_t)(c + 1) * NODE_PAD);
            s0.x += p0.x; s0.y += p0.y; s0.z += p0.z; s0.w += p0.w;
            s1.x += p1.x; s1.y += p1.y; s1.z += p1.z; s1.w += p1.w;
        }
    }
    float4 a4;
    a4.x = (s0.x + s1.x) * 0.01f;
    a4.y = (s0.y + s1.y) * 0.01f;
    a4.z = (s0.z + s1.z) * 0.01f;
    a4.w = (s0.w + s1.w) * 0.01f;

    // ---- layer 1: 8 col-tiles of 16, K=128 in 4 MFMA steps each
#pragma unroll
    for (int nt = 0; nt < 8; ++nt) {
        floatx4 acc = {0.f, 0.f, 0.f, 0.f};
        const short* wb = W1t + (size_t)(nt * 16 + m16) * 128 + quad * 8;
#pragma unroll
        for (int kc = 0; kc < 4; ++kc) {
            short8 bfr = *(const short8*)(wb + kc * 32);
            acc = __builtin_amdgcn_mfma_f32_16x16x32_bf16(a1[kc], bfr, acc, 0, 0, 0);
        }
        int col = nt * 16 + m16;
        float bias = b1[col];
        float wagg = W1[128 * HID + col];
        float av[4] = {a4.x, a4.y, a4.z, a4.w};
#pragma unroll
        for (int r = 0; r < 4; ++r) {
            float v = acc[r] + bias + av[r] * wagg;
            float sg = __builtin_amdgcn_rcpf(1.0f + __expf(-v));
            v *= sg;                       // silu
            t_lds[wv][(quad * 4 + r) * 136 + col] = f2bf(v);
        }
    }

    __syncthreads();   // LDS write -> read ordering (per-wave slices)

    // ---- A fragments for layer 2 from LDS (A-layout reads, 16B aligned)
    short8 a2[4];
#pragma unroll
    for (int kc = 0; kc < 4; ++kc)
        a2[kc] = *(const short8*)(&t_lds[wv][m16 * 136 + kc * 32 + quad * 8]);

    // ---- layer 2 + residual epilogue
#pragma unroll
    for (int nt = 0; nt < 8; ++nt) {
        floatx4 acc = {0.f, 0.f, 0.f, 0.f};
        const short* wb = W2t + (size_t)(nt * 16 + m16) * 128 + quad * 8;
#pragma unroll
        for (int kc = 0; kc < 4; ++kc) {
            short8 bfr = *(const short8*)(wb + kc * 32);
            acc = __builtin_amdgcn_mfma_f32_16x16x32_bf16(a2[kc], bfr, acc, 0, 0, 0);
        }
        int col = nt * 16 + m16;
        float bias = b2[col];
#pragma unroll
        for (int r = 0; r < 4; ++r) {
            int row = node0 + quad * 4 + r;
            if (row < n_nodes) {
                size_t off = (size_t)row * HID + col;
                out[off] = h[off] + acc[r] + bias;
            }
        }
    }
}

// ---------------------------------------------------------------------------
// Launch.  Inputs (setup_inputs order):
//  0 h[50000*128] f32 | 1 edges[2*800000] i32 | 2 distances[800000] f32
//  3..8 edge-MLP weights (DEAD CODE, unused)
//  9 W_n1[129*128] | 10 b_n1[128] | 11 W_n2[128*128] | 12 b_n2[128]
// d_ws layout: part f32[NPART][NODE_PAD] (25.6 MB) | W1t bf16[16K] | W2t bf16[16K]
// part needs no zeroing: scatter_lds overwrites every element.
// ---------------------------------------------------------------------------
extern "C" void kernel_launch(void* const* d_in, const int* in_sizes, int n_in,
                              void* d_out, int out_size, void* d_ws, size_t ws_size,
                              hipStream_t stream) {
    const float* h     = (const float*)d_in[0];
    const int*   edges = (const int*)d_in[1];
    const float* dist  = (const float*)d_in[2];
    const float* W1    = (const float*)d_in[9];
    const float* b1    = (const float*)d_in[10];
    const float* W2    = (const float*)d_in[11];
    const float* b2    = (const float*)d_in[12];
    float* out = (float*)d_out;

    const int n_nodes = in_sizes[0] / HID;
    const int n_edges = in_sizes[2];
    const int* rows = edges;   // edges[0, :]

    float* part = (float*)d_ws;
    short* W1t  = (short*)((char*)d_ws + (size_t)NPART * NODE_PAD * sizeof(float));
    short* W2t  = W1t + 16384;

    convert_weights<<<128, 256, 0, stream>>>(W1, W2, W1t, W2t);

    scatter_lds<<<NRANGE * NPART, 256, 0, stream>>>(rows, dist, part, n_edges);

    const int blocks = (n_nodes + 63) / 64;
    node_mlp_mfma<<<blocks, 256, 0, stream>>>(h, part, W1t, W2t, W1, b1, b2, out,
                                              n_nodes);
}

// Round 5
// 135.440 us; speedup vs baseline: 2.3503x; 1.2085x over previous
//
#include <hip/hip_runtime.h>

#define HID 128
#define NODE_PAD 50048   // padded node count (multiple of 16; covers 50000)
#define NRANGE 4         // node ranges (LDS histogram per range)
#define RANGE 12512      // NODE_PAD / NRANGE  (48.9 KB of LDS bins)
#define NPART 128        // edge chunks = partial aggregate buffers
#define NGRP 8           // reduced partial groups read by the MLP

typedef __attribute__((ext_vector_type(8))) short short8;   // bf16x8 A/B frag (4 VGPRs)
typedef __attribute__((ext_vector_type(4))) float floatx4;  // C/D frag

// fp32 -> bf16 (RNE) as raw short
__device__ __forceinline__ short f2bf(float f) {
    unsigned u = __builtin_bit_cast(unsigned, f);
    unsigned r = (u + 0x7FFFu + ((u >> 16) & 1u)) >> 16;
    return (short)r;
}

// ---------------------------------------------------------------------------
// Kernel 1: scatter-add with ZERO global atomics (round-3 lesson: device
// fp32 atomics bottleneck at ~19 G/s with 32 B write-through each).
// Block (r,b) bins node range r of edge chunk b into LDS, then streams the
// bins to part[b] with plain coalesced stores.
// ---------------------------------------------------------------------------
__global__ __launch_bounds__(256) void scatter_lds(const int* __restrict__ rows,
                                                   const float* __restrict__ dist,
                                                   float* __restrict__ part,
                                                   int n_edges) {
    __shared__ float bins[RANGE];
    const int r = blockIdx.x & (NRANGE - 1);
    const int b = blockIdx.x >> 2;
    const int base = r * RANGE;

    for (int i = threadIdx.x; i < RANGE / 4; i += 256)
        ((float4*)bins)[i] = make_float4(0.f, 0.f, 0.f, 0.f);
    __syncthreads();

    const int chunk = (n_edges + NPART - 1) / NPART;
    const int cbeg = b * chunk;
    const int cend = min(cbeg + chunk, n_edges);

    for (int i = cbeg + threadIdx.x * 4; i < cend; i += 256 * 4) {
        if (i + 4 <= cend) {
            int4   rr = *(const int4*)(rows + i);
            float4 dd = *(const float4*)(dist + i);
            if ((unsigned)(rr.x - base) < RANGE) atomicAdd(&bins[rr.x - base], dd.x);
            if ((unsigned)(rr.y - base) < RANGE) atomicAdd(&bins[rr.y - base], dd.y);
            if ((unsigned)(rr.z - base) < RANGE) atomicAdd(&bins[rr.z - base], dd.z);
            if ((unsigned)(rr.w - base) < RANGE) atomicAdd(&bins[rr.w - base], dd.w);
        } else {
            for (int j = i; j < cend; ++j) {
                int rw = rows[j];
                if ((unsigned)(rw - base) < RANGE) atomicAdd(&bins[rw - base], dist[j]);
            }
        }
    }
    __syncthreads();

    float4* dst = (float4*)(part + (size_t)b * NODE_PAD + base);
    for (int i = threadIdx.x; i < RANGE / 4; i += 256)
        dst[i] = ((const float4*)bins)[i];
}

// ---------------------------------------------------------------------------
// Kernel 2: reduce the 128 scatter partials down to NGRP=8 groups.
// Fully coalesced column sweep; round-4 lesson: doing this inside the MLP
// added 14 MB of fetch + a 64-deep strided load chain to a latency-bound
// kernel. Here it runs at streaming BW on 392 blocks.
// ---------------------------------------------------------------------------
__global__ __launch_bounds__(256) void reduce_partials(const float* __restrict__ part,
                                                       float* __restrict__ agg8) {
    const int g   = blockIdx.x & (NGRP - 1);
    const int blk = blockIdx.x >> 3;
    const int i   = blk * 256 + threadIdx.x;          // float4 column index
    const int nc4 = NODE_PAD / 4;
    if (i < nc4) {
        const float4* p = (const float4*)part + (size_t)g * 16 * nc4 + i;
        float4 s = make_float4(0.f, 0.f, 0.f, 0.f);
#pragma unroll
        for (int c = 0; c < 16; ++c) {
            float4 v = p[(size_t)c * nc4];
            s.x += v.x; s.y += v.y; s.z += v.z; s.w += v.w;
        }
        ((float4*)agg8)[(size_t)g * nc4 + i] = s;
    }
}

// ---------------------------------------------------------------------------
// Kernel 3: transpose + bf16-convert the two 128x128 weight blocks.
// W1t[n][k] = bf16(W1[k][n]), W2t[n][k] = bf16(W2[k][n]).  (W1 row 128, the
// agg row, stays fp32 and is applied in the epilogue.)
// ---------------------------------------------------------------------------
__global__ void convert_weights(const float* __restrict__ W1,
                                const float* __restrict__ W2,
                                short* __restrict__ W1t,
                                short* __restrict__ W2t) {
    int t = blockIdx.x * blockDim.x + threadIdx.x;   // 0..32767
    int idx = t & 16383;
    int n = idx & 127, k = idx >> 7;
    if (t < 16384) W1t[n * 128 + k] = f2bf(W1[k * 128 + n]);
    else           W2t[n * 128 + k] = f2bf(W2[k * 128 + n]);
}

// ---------------------------------------------------------------------------
// Kernel 4: node MLP via bf16 MFMA. 4 waves/block, each wave one 16-node
// tile. Weights are staged in LDS ONE LAYER AT A TIME into a reused 34.8 KB
// buffer (row stride 136 shorts -> 2-way bank aliasing = free), so B-frags
// come from ds_read_b128 (~12 cyc) instead of L2 (~200 cyc), and block LDS
// stays at 52.2 KB -> 3 blocks/CU = 12 waves/CU.
//   t = silu(h@W1 + agg*0.01*w_agg + b1); out = h + t@W2 + b2
// A-frag: lane holds A[m=lane&15][k=quad*8+j]; C/D: col=lane&15,
// row=quad*4+reg; t round-trips LDS to convert C-layout -> A-layout.
// ---------------------------------------------------------------------------
__global__ __launch_bounds__(256) void node_mlp_mfma(
    const float* __restrict__ h,
    const float* __restrict__ agg8,  // [NGRP][NODE_PAD]
    const short* __restrict__ W1t,   // [128][128] bf16 (n-major)
    const short* __restrict__ W2t,   // [128][128] bf16 (n-major)
    const float* __restrict__ W1,    // fp32, for row 128 (agg weight row)
    const float* __restrict__ b1,
    const float* __restrict__ b2,
    float* __restrict__ out,
    int n_nodes)
{
    __shared__ short WL[128 * 136];        // 34816 B, one layer at a time
    __shared__ short t_lds[4][16 * 136];   // 17408 B, per-wave t slices

    const int tid  = threadIdx.x;
    const int wv   = tid >> 6;
    const int lane = tid & 63;
    const int m16  = lane & 15;
    const int quad = lane >> 4;
    const int node0 = blockIdx.x * 64 + wv * 16;

    // ---- A fragments for layer 1 (h rows, fp32 -> bf16 in regs); issue early
    short8 a1[4];
    {
        int row = node0 + m16;
        if (row >= n_nodes) row = n_nodes - 1;
        const float* hr = h + (size_t)row * HID + quad * 8;
#pragma unroll
        for (int kc = 0; kc < 4; ++kc) {
            float4 x0 = *(const float4*)(hr + kc * 32);
            float4 x1 = *(const float4*)(hr + kc * 32 + 4);
            short8 v;
            v[0] = f2bf(x0.x); v[1] = f2bf(x0.y); v[2] = f2bf(x0.z); v[3] = f2bf(x0.w);
            v[4] = f2bf(x1.x); v[5] = f2bf(x1.y); v[6] = f2bf(x1.z); v[7] = f2bf(x1.w);
            a1[kc] = v;
        }
    }

    // agg for this lane's 4 C-rows: sum the 8 reduced groups, scale by 1/100
    float4 a4;
    {
        float4 s = make_float4(0.f, 0.f, 0.f, 0.f);
#pragma unroll
        for (int g = 0; g < NGRP; ++g) {
            float4 p = *(const float4*)(agg8 + (size_t)g * NODE_PAD + node0 + quad * 4);
            s.x += p.x; s.y += p.y; s.z += p.z; s.w += p.w;
        }
        a4.x = s.x * 0.01f; a4.y = s.y * 0.01f; a4.z = s.z * 0.01f; a4.w = s.w * 0.01f;
    }

    // ---- stage W1 into LDS (coalesced dwordx4; row n chunk c -> n*136 + c*8)
#pragma unroll
    for (int i = 0; i < 8; ++i) {
        int idx = tid + i * 256;             // 0..2047
        int n = idx >> 4, c = idx & 15;
        *(float4*)(WL + n * 136 + c * 8) = ((const float4*)W1t)[idx];
    }
    __syncthreads();

    // ---- layer 1: 8 col-tiles of 16, K=128 in 4 MFMA steps each
#pragma unroll
    for (int nt = 0; nt < 8; ++nt) {
        floatx4 acc = {0.f, 0.f, 0.f, 0.f};
        const short* wb = WL + (nt * 16 + m16) * 136 + quad * 8;
#pragma unroll
        for (int kc = 0; kc < 4; ++kc) {
            short8 bfr = *(const short8*)(wb + kc * 32);
            acc = __builtin_amdgcn_mfma_f32_16x16x32_bf16(a1[kc], bfr, acc, 0, 0, 0);
        }
        int col = nt * 16 + m16;
        float bias = b1[col];
        float wagg = W1[128 * HID + col];
        float av[4] = {a4.x, a4.y, a4.z, a4.w};
#pragma unroll
        for (int r = 0; r < 4; ++r) {
            float v = acc[r] + bias + av[r] * wagg;
            float sg = __builtin_amdgcn_rcpf(1.0f + __expf(-v));
            v *= sg;                       // silu
            t_lds[wv][(quad * 4 + r) * 136 + col] = f2bf(v);
        }
    }

    __syncthreads();   // all waves done with W1 reads (and t written)

    // ---- stage W2 into the SAME LDS buffer
#pragma unroll
    for (int i = 0; i < 8; ++i) {
        int idx = tid + i * 256;
        int n = idx >> 4, c = idx & 15;
        *(float4*)(WL + n * 136 + c * 8) = ((const float4*)W2t)[idx];
    }
    __syncthreads();

    // ---- A fragments for layer 2 from LDS (A-layout reads, 16B aligned)
    short8 a2[4];
#pragma unroll
    for (int kc = 0; kc < 4; ++kc)
        a2[kc] = *(const short8*)(&t_lds[wv][m16 * 136 + kc * 32 + quad * 8]);

    // ---- layer 2 + residual epilogue
#pragma unroll
    for (int nt = 0; nt < 8; ++nt) {
        floatx4 acc = {0.f, 0.f, 0.f, 0.f};
        const short* wb = WL + (nt * 16 + m16) * 136 + quad * 8;
#pragma unroll
        for (int kc = 0; kc < 4; ++kc) {
            short8 bfr = *(const short8*)(wb + kc * 32);
            acc = __builtin_amdgcn_mfma_f32_16x16x32_bf16(a2[kc], bfr, acc, 0, 0, 0);
        }
        int col = nt * 16 + m16;
        float bias = b2[col];
#pragma unroll
        for (int r = 0; r < 4; ++r) {
            int row = node0 + quad * 4 + r;
            if (row < n_nodes) {
                size_t off = (size_t)row * HID + col;
                out[off] = h[off] + acc[r] + bias;
            }
        }
    }
}

// ---------------------------------------------------------------------------
// Launch.  Inputs (setup_inputs order):
//  0 h[50000*128] f32 | 1 edges[2*800000] i32 | 2 distances[800000] f32
//  3..8 edge-MLP weights (DEAD CODE, unused)
//  9 W_n1[129*128] | 10 b_n1[128] | 11 W_n2[128*128] | 12 b_n2[128]
// d_ws: part f32[NPART][NODE_PAD] (25.6 MB) | agg8 f32[NGRP][NODE_PAD]
//       (1.6 MB) | W1t bf16[16K] | W2t bf16[16K].  No zeroing needed:
// scatter_lds/reduce_partials overwrite every element they produce.
// ---------------------------------------------------------------------------
extern "C" void kernel_launch(void* const* d_in, const int* in_sizes, int n_in,
                              void* d_out, int out_size, void* d_ws, size_t ws_size,
                              hipStream_t stream) {
    const float* h     = (const float*)d_in[0];
    const int*   edges = (const int*)d_in[1];
    const float* dist  = (const float*)d_in[2];
    const float* W1    = (const float*)d_in[9];
    const float* b1    = (const float*)d_in[10];
    const float* W2    = (const float*)d_in[11];
    const float* b2    = (const float*)d_in[12];
    float* out = (float*)d_out;

    const int n_nodes = in_sizes[0] / HID;
    const int n_edges = in_sizes[2];
    const int* rows = edges;   // edges[0, :]

    float* part = (float*)d_ws;
    float* agg8 = part + (size_t)NPART * NODE_PAD;
    short* W1t  = (short*)(agg8 + (size_t)NGRP * NODE_PAD);
    short* W2t  = W1t + 16384;

    convert_weights<<<128, 256, 0, stream>>>(W1, W2, W1t, W2t);

    scatter_lds<<<NRANGE * NPART, 256, 0, stream>>>(rows, dist, part, n_edges);

    reduce_partials<<<NGRP * ((NODE_PAD / 4 + 255) / 256), 256, 0, stream>>>(part, agg8);

    const int blocks = (n_nodes + 63) / 64;
    node_mlp_mfma<<<blocks, 256, 0, stream>>>(h, agg8, W1t, W2t, W1, b1, b2, out,
                                              n_nodes);
}

// Round 6
// 132.104 us; speedup vs baseline: 2.4097x; 1.0253x over previous
//
#include <hip/hip_runtime.h>

#define HID 128
#define NODE_PAD 50048   // padded node count (multiple of 16; covers 50000)
#define NRANGE 4         // node ranges (LDS histogram per range)
#define RANGE 12512      // NODE_PAD / NRANGE  (48.9 KB of LDS bins)
#define NPART 64         // edge chunks = partial aggregate buffers
#define NGRP 8           // reduced partial groups read by the MLP

typedef __attribute__((ext_vector_type(8))) short short8;   // bf16x8 A/B frag (4 VGPRs)
typedef __attribute__((ext_vector_type(4))) float floatx4;  // C/D frag

// fp32 -> bf16 (RNE) as raw short
__device__ __forceinline__ short f2bf(float f) {
    unsigned u = __builtin_bit_cast(unsigned, f);
    unsigned r = (u + 0x7FFFu + ((u >> 16) & 1u)) >> 16;
    return (short)r;
}

// ---------------------------------------------------------------------------
// Kernel 1: scatter-add with ZERO global atomics (round-3 lesson: device
// fp32 atomics bottleneck at ~19 G/s with 32 B write-through each).
// Block (r,b) bins node range r of edge chunk b into LDS, then streams the
// bins to part[b] with plain coalesced stores. NPART=64 keeps part traffic
// at 12.8 MB each way (round-5 lesson: part flush+reread was the scatter
// path's remaining cost).
// ---------------------------------------------------------------------------
__global__ __launch_bounds__(256) void scatter_lds(const int* __restrict__ rows,
                                                   const float* __restrict__ dist,
                                                   float* __restrict__ part,
                                                   int n_edges) {
    __shared__ float bins[RANGE];
    const int r = blockIdx.x & (NRANGE - 1);
    const int b = blockIdx.x >> 2;
    const int base = r * RANGE;

    for (int i = threadIdx.x; i < RANGE / 4; i += 256)
        ((float4*)bins)[i] = make_float4(0.f, 0.f, 0.f, 0.f);
    __syncthreads();

    const int chunk = (n_edges + NPART - 1) / NPART;
    const int cbeg = b * chunk;
    const int cend = min(cbeg + chunk, n_edges);

    for (int i = cbeg + threadIdx.x * 4; i < cend; i += 256 * 4) {
        if (i + 4 <= cend) {
            int4   rr = *(const int4*)(rows + i);
            float4 dd = *(const float4*)(dist + i);
            if ((unsigned)(rr.x - base) < RANGE) atomicAdd(&bins[rr.x - base], dd.x);
            if ((unsigned)(rr.y - base) < RANGE) atomicAdd(&bins[rr.y - base], dd.y);
            if ((unsigned)(rr.z - base) < RANGE) atomicAdd(&bins[rr.z - base], dd.z);
            if ((unsigned)(rr.w - base) < RANGE) atomicAdd(&bins[rr.w - base], dd.w);
        } else {
            for (int j = i; j < cend; ++j) {
                int rw = rows[j];
                if ((unsigned)(rw - base) < RANGE) atomicAdd(&bins[rw - base], dist[j]);
            }
        }
    }
    __syncthreads();

    float4* dst = (float4*)(part + (size_t)b * NODE_PAD + base);
    for (int i = threadIdx.x; i < RANGE / 4; i += 256)
        dst[i] = ((const float4*)bins)[i];
}

// ---------------------------------------------------------------------------
// Kernel 2: reduce the 64 scatter partials down to NGRP=8 groups (8 each).
// Fully coalesced column sweep (round-4 lesson: fusing this into the MLP
// added 14 MB of fetch + a deep strided load chain to a latency-bound
// kernel).
// ---------------------------------------------------------------------------
__global__ __launch_bounds__(256) void reduce_partials(const float* __restrict__ part,
                                                       float* __restrict__ agg8) {
    const int g   = blockIdx.x & (NGRP - 1);
    const int blk = blockIdx.x >> 3;
    const int i   = blk * 256 + threadIdx.x;          // float4 column index
    const int nc4 = NODE_PAD / 4;
    if (i < nc4) {
        const float4* p = (const float4*)part + (size_t)g * (NPART / NGRP) * nc4 + i;
        float4 s = make_float4(0.f, 0.f, 0.f, 0.f);
#pragma unroll
        for (int c = 0; c < NPART / NGRP; ++c) {
            float4 v = p[(size_t)c * nc4];
            s.x += v.x; s.y += v.y; s.z += v.z; s.w += v.w;
        }
        ((float4*)agg8)[(size_t)g * nc4 + i] = s;
    }
}

// ---------------------------------------------------------------------------
// Kernel 3: transpose + bf16-convert the two 128x128 weight blocks.
// W1t[n][k] = bf16(W1[k][n]), W2t[n][k] = bf16(W2[k][n]).  (W1 row 128, the
// agg row, stays fp32 and is applied in the epilogue.)
// ---------------------------------------------------------------------------
__global__ void convert_weights(const float* __restrict__ W1,
                                const float* __restrict__ W2,
                                short* __restrict__ W1t,
                                short* __restrict__ W2t) {
    int t = blockIdx.x * blockDim.x + threadIdx.x;   // 0..32767
    int idx = t & 16383;
    int n = idx & 127, k = idx >> 7;
    if (t < 16384) W1t[n * 128 + k] = f2bf(W1[k * 128 + n]);
    else           W2t[n * 128 + k] = f2bf(W2[k * 128 + n]);
}

// ---------------------------------------------------------------------------
// Kernel 4: node MLP via bf16 MFMA. 512-thread blocks = 8 waves sharing one
// staged-weight LDS buffer, each wave one 16-node tile. Weights staged ONE
// LAYER AT A TIME into a reused 34.8 KB buffer (row stride 136 shorts ->
// 2-way bank aliasing = free): B-frags come from ds_read_b128 (~12 cyc)
// instead of L2 (~200 cyc). Block LDS 69.6 KB -> 2 blocks/CU = 16 waves/CU
// (round-5 was 12), and half the blocks means half the weight re-staging
// and barrier work per node.
//   t = silu(h@W1 + agg*0.01*w_agg + b1); out = h + t@W2 + b2
// A-frag: lane holds A[m=lane&15][k=quad*8+j]; C/D: col=lane&15,
// row=quad*4+reg; t round-trips wave-private LDS (C-layout -> A-layout).
// ---------------------------------------------------------------------------
__global__ __launch_bounds__(512) void node_mlp_mfma(
    const float* __restrict__ h,
    const float* __restrict__ agg8,  // [NGRP][NODE_PAD]
    const short* __restrict__ W1t,   // [128][128] bf16 (n-major)
    const short* __restrict__ W2t,   // [128][128] bf16 (n-major)
    const float* __restrict__ W1,    // fp32, for row 128 (agg weight row)
    const float* __restrict__ b1,
    const float* __restrict__ b2,
    float* __restrict__ out,
    int n_nodes)
{
    __shared__ short WL[128 * 136];        // 34816 B, one layer at a time
    __shared__ short t_lds[8][16 * 136];   // 34816 B, per-wave t slices

    const int tid  = threadIdx.x;
    const int wv   = tid >> 6;
    const int lane = tid & 63;
    const int m16  = lane & 15;
    const int quad = lane >> 4;
    const int node0 = blockIdx.x * 128 + wv * 16;

    // ---- A fragments for layer 1 (h rows, fp32 -> bf16 in regs); issue early
    short8 a1[4];
    {
        int row = node0 + m16;
        if (row >= n_nodes) row = n_nodes - 1;
        const float* hr = h + (size_t)row * HID + quad * 8;
#pragma unroll
        for (int kc = 0; kc < 4; ++kc) {
            float4 x0 = *(const float4*)(hr + kc * 32);
            float4 x1 = *(const float4*)(hr + kc * 32 + 4);
            short8 v;
            v[0] = f2bf(x0.x); v[1] = f2bf(x0.y); v[2] = f2bf(x0.z); v[3] = f2bf(x0.w);
            v[4] = f2bf(x1.x); v[5] = f2bf(x1.y); v[6] = f2bf(x1.z); v[7] = f2bf(x1.w);
            a1[kc] = v;
        }
    }

    // agg for this lane's 4 C-rows: sum the 8 reduced groups, scale by 1/100
    float4 a4;
    {
        float4 s = make_float4(0.f, 0.f, 0.f, 0.f);
#pragma unroll
        for (int g = 0; g < NGRP; ++g) {
            float4 p = *(const float4*)(agg8 + (size_t)g * NODE_PAD + node0 + quad * 4);
            s.x += p.x; s.y += p.y; s.z += p.z; s.w += p.w;
        }
        a4.x = s.x * 0.01f; a4.y = s.y * 0.01f; a4.z = s.z * 0.01f; a4.w = s.w * 0.01f;
    }

    // ---- stage W1 into LDS (coalesced dwordx4; row n chunk c -> n*136 + c*8)
#pragma unroll
    for (int i = 0; i < 4; ++i) {
        int idx = tid + i * 512;             // 0..2047
        int n = idx >> 4, c = idx & 15;
        *(float4*)(WL + n * 136 + c * 8) = ((const float4*)W1t)[idx];
    }
    __syncthreads();

    // ---- layer 1: 8 col-tiles of 16, K=128 in 4 MFMA steps each
#pragma unroll
    for (int nt = 0; nt < 8; ++nt) {
        floatx4 acc = {0.f, 0.f, 0.f, 0.f};
        const short* wb = WL + (nt * 16 + m16) * 136 + quad * 8;
#pragma unroll
        for (int kc = 0; kc < 4; ++kc) {
            short8 bfr = *(const short8*)(wb + kc * 32);
            acc = __builtin_amdgcn_mfma_f32_16x16x32_bf16(a1[kc], bfr, acc, 0, 0, 0);
        }
        int col = nt * 16 + m16;
        float bias = b1[col];
        float wagg = W1[128 * HID + col];
        float av[4] = {a4.x, a4.y, a4.z, a4.w};
#pragma unroll
        for (int r = 0; r < 4; ++r) {
            float v = acc[r] + bias + av[r] * wagg;
            float sg = __builtin_amdgcn_rcpf(1.0f + __expf(-v));
            v *= sg;                       // silu
            t_lds[wv][(quad * 4 + r) * 136 + col] = f2bf(v);
        }
    }

    __syncthreads();   // all waves done reading W1 before overwrite

    // ---- stage W2 into the SAME LDS buffer
#pragma unroll
    for (int i = 0; i < 4; ++i) {
        int idx = tid + i * 512;
        int n = idx >> 4, c = idx & 15;
        *(float4*)(WL + n * 136 + c * 8) = ((const float4*)W2t)[idx];
    }
    __syncthreads();

    // ---- A fragments for layer 2 from LDS (A-layout reads, 16B aligned)
    short8 a2[4];
#pragma unroll
    for (int kc = 0; kc < 4; ++kc)
        a2[kc] = *(const short8*)(&t_lds[wv][m16 * 136 + kc * 32 + quad * 8]);

    // ---- layer 2 + residual epilogue
#pragma unroll
    for (int nt = 0; nt < 8; ++nt) {
        floatx4 acc = {0.f, 0.f, 0.f, 0.f};
        const short* wb = WL + (nt * 16 + m16) * 136 + quad * 8;
#pragma unroll
        for (int kc = 0; kc < 4; ++kc) {
            short8 bfr = *(const short8*)(wb + kc * 32);
            acc = __builtin_amdgcn_mfma_f32_16x16x32_bf16(a2[kc], bfr, acc, 0, 0, 0);
        }
        int col = nt * 16 + m16;
        float bias = b2[col];
#pragma unroll
        for (int r = 0; r < 4; ++r) {
            int row = node0 + quad * 4 + r;
            if (row < n_nodes) {
                size_t off = (size_t)row * HID + col;
                out[off] = h[off] + acc[r] + bias;
            }
        }
    }
}

// ---------------------------------------------------------------------------
// Launch.  Inputs (setup_inputs order):
//  0 h[50000*128] f32 | 1 edges[2*800000] i32 | 2 distances[800000] f32
//  3..8 edge-MLP weights (DEAD CODE, unused)
//  9 W_n1[129*128] | 10 b_n1[128] | 11 W_n2[128*128] | 12 b_n2[128]
// d_ws: part f32[NPART][NODE_PAD] (12.8 MB) | agg8 f32[NGRP][NODE_PAD]
//       (1.6 MB) | W1t bf16[16K] | W2t bf16[16K].  No zeroing needed:
// scatter_lds/reduce_partials overwrite every element they produce.
// ---------------------------------------------------------------------------
extern "C" void kernel_launch(void* const* d_in, const int* in_sizes, int n_in,
                              void* d_out, int out_size, void* d_ws, size_t ws_size,
                              hipStream_t stream) {
    const float* h     = (const float*)d_in[0];
    const int*   edges = (const int*)d_in[1];
    const float* dist  = (const float*)d_in[2];
    const float* W1    = (const float*)d_in[9];
    const float* b1    = (const float*)d_in[10];
    const float* W2    = (const float*)d_in[11];
    const float* b2    = (const float*)d_in[12];
    float* out = (float*)d_out;

    const int n_nodes = in_sizes[0] / HID;
    const int n_edges = in_sizes[2];
    const int* rows = edges;   // edges[0, :]

    float* part = (float*)d_ws;
    float* agg8 = part + (size_t)NPART * NODE_PAD;
    short* W1t  = (short*)(agg8 + (size_t)NGRP * NODE_PAD);
    short* W2t  = W1t + 16384;

    convert_weights<<<128, 256, 0, stream>>>(W1, W2, W1t, W2t);

    scatter_lds<<<NRANGE * NPART, 256, 0, stream>>>(rows, dist, part, n_edges);

    reduce_partials<<<NGRP * ((NODE_PAD / 4 + 255) / 256), 256, 0, stream>>>(part, agg8);

    const int blocks = (n_nodes + 127) / 128;
    node_mlp_mfma<<<blocks, 512, 0, stream>>>(h, agg8, W1t, W2t, W1, b1, b2, out,
                                              n_nodes);
}